// Round 5
// baseline (171.940 us; speedup 1.0000x reference)
//
#include <hip/hip_runtime.h>
#include <hip/hip_bf16.h>
#include <cstdint>
#include <cstddef>

#define B_DIM 256
#define T_DIM 256
#define EMB   384
#define HEAD  64

typedef __attribute__((ext_vector_type(8))) short bf16x8;
typedef __attribute__((ext_vector_type(4))) float f32x4;
typedef __attribute__((ext_vector_type(4))) unsigned int u32x4;

__device__ __forceinline__ unsigned short f2bf(float f) {
    union { float f; unsigned int u; } v; v.f = f;
    unsigned int r = v.u + 0x7fffu + ((v.u >> 16) & 1u);  // RNE
    return (unsigned short)(r >> 16);
}

__device__ __forceinline__ unsigned int pkbf(float a, float b) {
#if __has_builtin(__builtin_amdgcn_cvt_pk_bf16_f32)
    typedef __attribute__((ext_vector_type(2))) __bf16 bf16x2_t;
    bf16x2_t r = __builtin_amdgcn_cvt_pk_bf16_f32(a, b);
    return *(unsigned int*)&r;
#else
    return (unsigned)f2bf(a) | ((unsigned)f2bf(b) << 16);
#endif
}

// ---------------------------------------------------------------------------
// Kernel 0: W prep — Wq|Wk|Wv fp32 [384][64] -> Wb bf16, chunk-permuted for
// global_load_lds staging; XOR-swizzled so the unpadded LDS image is
// conflict-free for the swizzled fragment reads.
// ---------------------------------------------------------------------------
__global__ void wprep_kernel(const float* __restrict__ Wq, const float* __restrict__ Wk,
                             const float* __restrict__ Wv, unsigned short* __restrict__ Wb) {
    int g = blockIdx.x * blockDim.x + threadIdx.x;
    if (g >= 9216) return;                 // 6 k-steps * 1536 chunks
    int kkstep = g / 1536, rem = g - kkstep * 1536;
    int r = rem >> 3, cs = rem & 7, c = cs ^ (r & 7);
    const float* W = (r < 64) ? Wq : (r < 128) ? Wk : Wv;
    int h = r & 63;
    unsigned short tmp[8];
#pragma unroll
    for (int e = 0; e < 8; ++e) {
        int k = kkstep * 64 + c * 8 + e;
        tmp[e] = f2bf(W[k * HEAD + h]);
    }
    *(u32x4*)(Wb + (size_t)g * 8) = *(u32x4*)tmp;
}

// ---------------------------------------------------------------------------
// Fused kernel: one block per batch, 512 threads (8 waves), 1 block/CU.
// Phase 1: QKV GEMM with A=W-frag, B=X-frag -> D[ch][tok]: lane's 4 acc regs
//   are channel-contiguous, so q/k scatter packs into ds_write_b64.
//   Xs+Ws double-buffered, one barrier per k-step, W via global_load_lds(16B).
// Phase 2: attention fully in LDS. Wave w owns row-tiles {w, 15-w} (17
//   col-tiles each — balanced). Both tiles processed in ONE jc loop with
//   shared K/V fragment loads and dual wave-private P strips (2x chain ILP).
// ---------------------------------------------------------------------------
__global__ __launch_bounds__(512, 2) void fused_kernel(const float* __restrict__ x,
                                                       const unsigned short* __restrict__ Wb,
                                                       float* __restrict__ out) {
    __shared__ union SM {
        struct { unsigned short Xs[2][256][72]; unsigned short Ws[2][12288]; } p1;   // 122,880 B
        struct { unsigned short qs[256][72]; unsigned short ks[256][72];
                 unsigned short vT[64][264]; unsigned short Ps[8][2][16][72]; } p2;  // 144,384 B
    } sm;

    const int tid = threadIdx.x;
    const int w = tid >> 6, lane = tid & 63, qd = lane >> 4, l15 = lane & 15;
    const int mh = w >> 1, nh = w & 1;
    const int b = blockIdx.x;
    const float* xb = x + (size_t)b * T_DIM * EMB;
    const int xrow = tid >> 4, xc4 = (tid & 15) << 2;

    f32x4 acc[6][4];   // [channel-tile][token-tile]
#pragma unroll
    for (int ct = 0; ct < 6; ++ct)
#pragma unroll
        for (int tt = 0; tt < 4; ++tt) acc[ct][tt] = (f32x4){0.f, 0.f, 0.f, 0.f};

    float4 xr[8];
    // prologue: W(0) glds + x(0) load + convert into buffers 0
#pragma unroll
    for (int s = 0; s < 3; ++s) {
        int idx = s * 512 + w * 64;  // wave-uniform base
        const unsigned short* gp = Wb + (size_t)(idx + lane) * 8;
        unsigned short* lp = &sm.p1.Ws[0][idx * 8];
        __builtin_amdgcn_global_load_lds(
            (const __attribute__((address_space(1))) unsigned int*)gp,
            (__attribute__((address_space(3))) unsigned int*)lp, 16, 0, 0);
    }
#pragma unroll
    for (int s = 0; s < 8; ++s)
        xr[s] = *(const float4*)(xb + (size_t)(xrow + 32 * s) * EMB + xc4);
#pragma unroll
    for (int s = 0; s < 8; ++s)
        *(uint2*)&sm.p1.Xs[0][xrow + 32 * s][xc4] = make_uint2(pkbf(xr[s].x, xr[s].y), pkbf(xr[s].z, xr[s].w));

    for (int kk = 0; kk < 6; ++kk) {
        __syncthreads();   // buffers[kk&1] ready (LDS writes + glds vmcnt drained)
        if (kk < 5) {      // prefetch into buffers[(kk+1)&1]
#pragma unroll
            for (int s = 0; s < 3; ++s) {
                int idx = s * 512 + w * 64;
                const unsigned short* gp = Wb + (size_t)((kk + 1) * 1536 + idx + lane) * 8;
                unsigned short* lp = &sm.p1.Ws[(kk + 1) & 1][idx * 8];
                __builtin_amdgcn_global_load_lds(
                    (const __attribute__((address_space(1))) unsigned int*)gp,
                    (__attribute__((address_space(3))) unsigned int*)lp, 16, 0, 0);
            }
#pragma unroll
            for (int s = 0; s < 8; ++s)
                xr[s] = *(const float4*)(xb + (size_t)(xrow + 32 * s) * EMB + (kk + 1) * 64 + xc4);
        }
#pragma unroll
        for (int kb = 0; kb < 2; ++kb) {
            bf16x8 xf[4], wf[6];
#pragma unroll
            for (int tt = 0; tt < 4; ++tt)
                xf[tt] = *(const bf16x8*)&sm.p1.Xs[kk & 1][64 * mh + 16 * tt + l15][32 * kb + 8 * qd];
#pragma unroll
            for (int ct = 0; ct < 6; ++ct) {
                int n = 96 * nh + 16 * ct + l15;
                wf[ct] = *(const bf16x8*)&sm.p1.Ws[kk & 1][n * 64 + (((4 * kb + qd) ^ (n & 7)) << 3)];
            }
#pragma unroll
            for (int ct = 0; ct < 6; ++ct)
#pragma unroll
                for (int tt = 0; tt < 4; ++tt)
                    acc[ct][tt] = __builtin_amdgcn_mfma_f32_16x16x32_bf16(wf[ct], xf[tt], acc[ct][tt], 0, 0, 0);
        }
        if (kk < 5) {      // convert next X tile after compute
#pragma unroll
            for (int s = 0; s < 8; ++s)
                *(uint2*)&sm.p1.Xs[(kk + 1) & 1][xrow + 32 * s][xc4] =
                    make_uint2(pkbf(xr[s].x, xr[s].y), pkbf(xr[s].z, xr[s].w));
        }
    }
    __syncthreads();       // all GEMM LDS reads done; safe to repurpose union

    // scatter acc -> qs / ks / vT.  D layout: row(=channel)=4*qd+reg, col(=token)=l15.
    // q/k: 4 contiguous channels per lane -> packed b64 writes.
#pragma unroll
    for (int ct = 0; ct < 6; ++ct) {
        int chBase = 96 * nh + 16 * ct;        // wave-uniform, no 64-boundary straddle
        int arr = chBase >> 6;
        int lch = (chBase & 63) + 4 * qd;
#pragma unroll
        for (int tt = 0; tt < 4; ++tt) {
            int tok = 64 * mh + 16 * tt + l15;
            uint2 pk2 = make_uint2(pkbf(acc[ct][tt][0], acc[ct][tt][1]),
                                   pkbf(acc[ct][tt][2], acc[ct][tt][3]));
            if (arr == 0)      *(uint2*)&sm.p2.qs[tok][lch] = pk2;
            else if (arr == 1) *(uint2*)&sm.p2.ks[tok][lch] = pk2;
            else {
                const unsigned short* pp = (const unsigned short*)&pk2;
#pragma unroll
                for (int reg = 0; reg < 4; ++reg) sm.p2.vT[lch + reg][tok] = pp[reg];
            }
        }
    }
    __syncthreads();       // q/k/vT ready

    // ---------------- attention, fully in LDS ----------------
    const int t0 = w, t1 = 15 - w;
    bf16x8 aq0[2], aq1[2];
#pragma unroll
    for (int kbi = 0; kbi < 2; ++kbi) {
        aq0[kbi] = *(const bf16x8*)&sm.p2.qs[16 * t0 + l15][32 * kbi + 8 * qd];
        aq1[kbi] = *(const bf16x8*)&sm.p2.qs[16 * t1 + l15][32 * kbi + 8 * qd];
    }

    f32x4 O[2][4];
    float l[2][4];
#pragma unroll
    for (int ti = 0; ti < 2; ++ti) {
#pragma unroll
        for (int dn = 0; dn < 4; ++dn) O[ti][dn] = (f32x4){0.f, 0.f, 0.f, 0.f};
#pragma unroll
        for (int reg = 0; reg < 4; ++reg) l[ti][reg] = 0.f;
    }

    const float cExp = 1.4426950408889634f / 19.595917942265423f; // log2(e)/sqrt(384)

    for (int jc = 0; jc < 5; ++jc) {
        const bool a0 = (4 * jc <= t0), a1 = (4 * jc <= t1);   // wave-uniform
        if (!a0 && !a1) continue;
        const int nm0 = a0 ? min(3, t0 - 4 * jc) : -1;
        const int nm1 = a1 ? min(3, t1 - 4 * jc) : -1;
        const int nmx = nm0 > nm1 ? nm0 : nm1;

        // shared K fragments for this jc
        bf16x8 kf[4][2];
#pragma unroll
        for (int nt = 0; nt < 4; ++nt)
            if (nt <= nmx) {
                kf[nt][0] = *(const bf16x8*)&sm.p2.ks[64 * jc + 16 * nt + l15][8 * qd];
                kf[nt][1] = *(const bf16x8*)&sm.p2.ks[64 * jc + 16 * nt + l15][32 + 8 * qd];
            }
        // QK MFMAs — both tiles' chains interleave
        f32x4 S0[4], S1[4];
#pragma unroll
        for (int nt = 0; nt < 4; ++nt) {
            if (nt <= nm0) {
                f32x4 s = __builtin_amdgcn_mfma_f32_16x16x32_bf16(aq0[0], kf[nt][0], (f32x4){0.f,0.f,0.f,0.f}, 0, 0, 0);
                S0[nt] = __builtin_amdgcn_mfma_f32_16x16x32_bf16(aq0[1], kf[nt][1], s, 0, 0, 0);
            }
            if (nt <= nm1) {
                f32x4 s = __builtin_amdgcn_mfma_f32_16x16x32_bf16(aq1[0], kf[nt][0], (f32x4){0.f,0.f,0.f,0.f}, 0, 0, 0);
                S1[nt] = __builtin_amdgcn_mfma_f32_16x16x32_bf16(aq1[1], kf[nt][1], s, 0, 0, 0);
            }
        }
        // exp + causal mask + row-sum + strip write (wave-private, no barrier)
        if (a0) {
#pragma unroll
            for (int nt = 0; nt < 4; ++nt)
#pragma unroll
                for (int reg = 0; reg < 4; ++reg) {
                    float p = 0.0f;
                    if (nt <= nm0) {
                        p = exp2f(S0[nt][reg] * cExp);
                        if (4 * jc + nt == t0 && (l15 > 4 * qd + reg)) p = 0.0f;
                    }
                    l[0][reg] += p;
                    sm.p2.Ps[w][0][4 * qd + reg][16 * nt + l15] = f2bf(p);
                }
        }
        if (a1) {
#pragma unroll
            for (int nt = 0; nt < 4; ++nt)
#pragma unroll
                for (int reg = 0; reg < 4; ++reg) {
                    float p = 0.0f;
                    if (nt <= nm1) {
                        p = exp2f(S1[nt][reg] * cExp);
                        if (4 * jc + nt == t1 && (l15 > 4 * qd + reg)) p = 0.0f;
                    }
                    l[1][reg] += p;
                    sm.p2.Ps[w][1][4 * qd + reg][16 * nt + l15] = f2bf(p);
                }
        }
        // P strips C->A layout; shared V fragments; PV for both tiles
        bf16x8 ap0a, ap0b, ap1a, ap1b;
        if (a0) { ap0a = *(const bf16x8*)&sm.p2.Ps[w][0][l15][8 * qd];
                  ap0b = *(const bf16x8*)&sm.p2.Ps[w][0][l15][32 + 8 * qd]; }
        if (a1) { ap1a = *(const bf16x8*)&sm.p2.Ps[w][1][l15][8 * qd];
                  ap1b = *(const bf16x8*)&sm.p2.Ps[w][1][l15][32 + 8 * qd]; }
#pragma unroll
        for (int dn = 0; dn < 4; ++dn) {
            bf16x8 bv0 = *(const bf16x8*)&sm.p2.vT[16 * dn + l15][64 * jc + 8 * qd];
            bf16x8 bv1 = *(const bf16x8*)&sm.p2.vT[16 * dn + l15][64 * jc + 32 + 8 * qd];
            if (a0) {
                O[0][dn] = __builtin_amdgcn_mfma_f32_16x16x32_bf16(ap0a, bv0, O[0][dn], 0, 0, 0);
                O[0][dn] = __builtin_amdgcn_mfma_f32_16x16x32_bf16(ap0b, bv1, O[0][dn], 0, 0, 0);
            }
            if (a1) {
                O[1][dn] = __builtin_amdgcn_mfma_f32_16x16x32_bf16(ap1a, bv0, O[1][dn], 0, 0, 0);
                O[1][dn] = __builtin_amdgcn_mfma_f32_16x16x32_bf16(ap1b, bv1, O[1][dn], 0, 0, 0);
            }
        }
    }

    const int tiles[2] = { t0, t1 };
#pragma unroll
    for (int ti = 0; ti < 2; ++ti) {
#pragma unroll
        for (int reg = 0; reg < 4; ++reg) {
            float s = l[ti][reg];
            s += __shfl_xor(s, 1);
            s += __shfl_xor(s, 2);
            s += __shfl_xor(s, 4);
            s += __shfl_xor(s, 8);
            float inv = 1.0f / s;
            int row = 16 * tiles[ti] + 4 * qd + reg;
            float* dst = out + ((size_t)b * T_DIM + row) * HEAD;
#pragma unroll
            for (int dn = 0; dn < 4; ++dn)
                __builtin_nontemporal_store(O[ti][dn][reg] * inv, dst + 16 * dn + l15);
        }
    }
}

// ---------------------------------------------------------------------------
extern "C" void kernel_launch(void* const* d_in, const int* in_sizes, int n_in,
                              void* d_out, int out_size, void* d_ws, size_t ws_size,
                              hipStream_t stream) {
    const float* x  = (const float*)d_in[0];
    const float* Wq = (const float*)d_in[1];
    const float* Wk = (const float*)d_in[2];
    const float* Wv = (const float*)d_in[3];
    float* out = (float*)d_out;

    unsigned short* Wb = (unsigned short*)d_ws;   // 9216*8 bf16 = 147 KB

    wprep_kernel<<<36, 256, 0, stream>>>(Wq, Wk, Wv, Wb);
    fused_kernel<<<B_DIM, 512, 0, stream>>>(x, Wb, out);
}